// Round 3
// baseline (498.923 us; speedup 1.0000x reference)
//
#include <hip/hip_runtime.h>

#define DIM 32
#define BLOCK 256

// ---------------------------------------------------------------------------
// Closed form of the Gibbs sweep:
//   step i: x_i = mu_i + sum_{j<i} C[i][j] x_new_j + sum_{j>i} C[i][j] x_old_j
//                 + s_i n_i,   C[i][j] = -P[i][j]/P[i][i] (off-diag), s_i=sqrt(1/P_ii)
// => x_new = Lc x_new + (m + Uc x_old + s.*n)
// => x_new = w + A x_old + Ts n,  T=(I-Lc)^{-1}, A=T*Uc, Ts=T*diag(s), w=T*m.
// ws layout (floats): [0,1024)  A   column-major (col j at 32*j)
//                     [1024,2048) Ts column-major (lower-triangular)
//                     [2048,2080) w
// ---------------------------------------------------------------------------

__global__ __launch_bounds__(1024) void gibbs_setup_kernel(
    const float* __restrict__ prec,
    const float* __restrict__ mu,
    float* __restrict__ ws)
{
    __shared__ float Cl[DIM * DIM];
    __shared__ float Tl[DIM * DIM];
    __shared__ float sl[DIM];
    __shared__ float ml[DIM];

    const int t = threadIdx.x;          // 0..1023
    const int i = t >> 5;
    const int j = t & 31;

    // Folded coefficients C (one element per thread)
    {
        const float pii = prec[i * DIM + i];
        Cl[t] = (i == j) ? 0.0f : (-prec[t] / pii);
    }
    if (t < DIM) {
        sl[t] = sqrtf(1.0f / prec[t * DIM + t]);
        ml[t] = mu[t];
    }
    __syncthreads();

    // T = (I - Lc)^{-1}: thread t (<32) forward-substitutes column t.
    if (t < DIM) {
        for (int r = 0; r < DIM; ++r) Tl[r * DIM + t] = (r == t) ? 1.0f : 0.0f;
        for (int r = t + 1; r < DIM; ++r) {
            float acc = 0.0f;
            for (int k = t; k < r; ++k)
                acc = fmaf(Cl[r * DIM + k], Tl[k * DIM + t], acc);
            Tl[r * DIM + t] = acc;
        }
    }
    __syncthreads();

    // A[i][j] = sum_{k<j} T[i][k] * C[k][j]   (column-major store)
    {
        float a = 0.0f;
        for (int k = 0; k < j; ++k)
            a = fmaf(Tl[i * DIM + k], Cl[k * DIM + j], a);
        ws[j * DIM + i] = a;
    }
    // Ts[i][j] = T[i][j] * s[j]               (column-major store)
    ws[DIM * DIM + j * DIM + i] = Tl[i * DIM + j] * sl[j];
    // w = T * m
    if (j == 0) {
        float wv = 0.0f;
        for (int k = 0; k <= i; ++k)
            wv = fmaf(Tl[i * DIM + k], ml[k], wv);
        ws[2 * DIM * DIM + i] = wv;
    }
}

// One thread = one row. Column-streaming matvec: 32 fp32 accumulators,
// wave-uniform coefficient columns (SGPR broadcast), no serial dependency.
__global__ __launch_bounds__(BLOCK, 4) void gibbs_matvec_kernel(
    const float* __restrict__ x,
    const float* __restrict__ noise,
    const float* __restrict__ ws,
    float* __restrict__ out)
{
    const float* __restrict__ GA = ws;                 // A  (col-major)
    const float* __restrict__ GN = ws + DIM * DIM;     // Ts (col-major, lower-tri)
    const float* __restrict__ W  = ws + 2 * DIM * DIM; // w

    const long row = (long)blockIdx.x * BLOCK + threadIdx.x;
    const float4* __restrict__ xp  = (const float4*)(x + row * DIM);
    const float4* __restrict__ np4 = (const float4*)(noise + row * DIM);
    float4* __restrict__ op = (float4*)(out + row * DIM);

    float acc[DIM];
#pragma unroll
    for (int i = 0; i < DIM; ++i) acc[i] = W[i];

    // x contribution: acc += A[:,j] * x_j   (column 0 of A is structurally 0)
#pragma unroll
    for (int q = 0; q < DIM / 4; ++q) {
        const float4 v = xp[q];
#pragma unroll
        for (int c = 0; c < 4; ++c) {
            const int j = q * 4 + c;
            if (j >= 1) {
                const float xj = (c == 0) ? v.x : (c == 1) ? v.y : (c == 2) ? v.z : v.w;
                const float* __restrict__ col = GA + j * DIM;
#pragma unroll
                for (int i = 0; i < DIM; ++i)
                    acc[i] = fmaf(col[i], xj, acc[i]);
            }
        }
    }

    // noise contribution: acc += Ts[:,j] * n_j   (Ts lower-triangular: i >= j)
#pragma unroll
    for (int q = 0; q < DIM / 4; ++q) {
        const float4 v = np4[q];
#pragma unroll
        for (int c = 0; c < 4; ++c) {
            const int j = q * 4 + c;
            const float nj = (c == 0) ? v.x : (c == 1) ? v.y : (c == 2) ? v.z : v.w;
            const float* __restrict__ col = GN + j * DIM;
#pragma unroll
            for (int i = j; i < DIM; ++i)
                acc[i] = fmaf(col[i], nj, acc[i]);
        }
    }

    op[0] = make_float4(acc[0],  acc[1],  acc[2],  acc[3]);
    op[1] = make_float4(acc[4],  acc[5],  acc[6],  acc[7]);
    op[2] = make_float4(acc[8],  acc[9],  acc[10], acc[11]);
    op[3] = make_float4(acc[12], acc[13], acc[14], acc[15]);
    op[4] = make_float4(acc[16], acc[17], acc[18], acc[19]);
    op[5] = make_float4(acc[20], acc[21], acc[22], acc[23]);
    op[6] = make_float4(acc[24], acc[25], acc[26], acc[27]);
    op[7] = make_float4(acc[28], acc[29], acc[30], acc[31]);
}

extern "C" void kernel_launch(void* const* d_in, const int* in_sizes, int n_in,
                              void* d_out, int out_size, void* d_ws, size_t ws_size,
                              hipStream_t stream) {
    const float* x     = (const float*)d_in[0];  // (B, 32)
    const float* noise = (const float*)d_in[1];  // (B, 32)
    const float* prec  = (const float*)d_in[2];  // (32, 32)
    const float* mu    = (const float*)d_in[3];  // (32,)
    float* out = (float*)d_out;
    float* ws  = (float*)d_ws;                   // needs 2080 floats (8.3 KB)

    const int B = in_sizes[0] / DIM;             // 1048576
    const int grid = B / BLOCK;                  // 4096 blocks

    gibbs_setup_kernel<<<1, 1024, 0, stream>>>(prec, mu, ws);
    gibbs_matvec_kernel<<<grid, BLOCK, 0, stream>>>(x, noise, ws, out);
}